// Round 4
// baseline (194.405 us; speedup 1.0000x reference)
//
#include <hip/hip_runtime.h>

#define BB   8
#define NBL  2000
#define RR   10000
#define XDIM 2000
#define NBLK 500          // GEMM blocks (co-resident: 2/CU on 256 CUs)
#define SELB 40           // blocks doing order-stat select
#define GEMB 100          // blocks doing the MLP GEMV

// tiny node: re-arm barrier counters every call (ws is poisoned, not re-zeroed)
__global__ void k_init(unsigned* __restrict__ counters) {
    if (threadIdx.x < 2) counters[threadIdx.x] = 0u;
}

__device__ __forceinline__ unsigned sortkey(float f) {
    unsigned u = __float_as_uint(f);
    return (u & 0x80000000u) ? ~u : (u | 0x80000000u);
}
__device__ __forceinline__ float unsortkey(unsigned u) {
    unsigned ub = (u & 0x80000000u) ? (u ^ 0x80000000u) : ~u;
    return __uint_as_float(ub);
}

__global__ __launch_bounds__(256, 2) void k_fused(
    const float* __restrict__ in1, const float* __restrict__ in2,
    const float* __restrict__ in3, const float* __restrict__ in4,
    const float* __restrict__ in5,
    const float* __restrict__ Wfc,  const float* __restrict__ bfc,
    const float* __restrict__ bfv,
    const float* __restrict__ Wmlp, const float* __restrict__ bmlp,
    float* __restrict__ mem2, float* __restrict__ spike_out,
    float* __restrict__ out, unsigned* __restrict__ counters)
{
    const int tid  = threadIdx.x;
    const int blk  = blockIdx.x;
    const int wave = tid >> 6, lane = tid & 63;

    // ================= phase 1: GEMM  mem2[q][b][nb] = x[b]·W_fc[nb*5+q] + biases
    {
        const int nb    = blk * 4 + wave;            // 0..1999
        const int rbase = nb * 5;

        float acc[5][BB];
        #pragma unroll
        for (int q = 0; q < 5; ++q)
            #pragma unroll
            for (int b = 0; b < BB; ++b) acc[q][b] = 0.f;

        #pragma unroll
        for (int i = 0; i < 8; ++i) {
            const int col = i * 256 + (lane << 2);   // float4-aligned, 0..2044
            const bool valid = col < XDIM;           // i==7: lanes >=52 idle
            const int wh  = col / 400;               // concat segment
            const int off = col - wh * 400;          // f4 never crosses segment edge
            const float* xp = in1;
            xp = (wh == 1) ? in2 : xp;
            xp = (wh == 2) ? in3 : xp;
            xp = (wh == 3) ? in4 : xp;
            xp = (wh == 4) ? in5 : xp;

            float4 w[5];
            #pragma unroll
            for (int q = 0; q < 5; ++q)
                w[q] = valid ? *(const float4*)(Wfc + (size_t)(rbase + q) * XDIM + col)
                             : make_float4(0.f, 0.f, 0.f, 0.f);

            #pragma unroll
            for (int b = 0; b < BB; ++b) {
                float4 xv = valid ? *(const float4*)(xp + b * 400 + off)
                                  : make_float4(0.f, 0.f, 0.f, 0.f);
                #pragma unroll
                for (int q = 0; q < 5; ++q)
                    acc[q][b] += w[q].x * xv.x + w[q].y * xv.y + w[q].z * xv.z + w[q].w * xv.w;
            }
        }

        #pragma unroll
        for (int q = 0; q < 5; ++q) {
            const int r = rbase + q;
            #pragma unroll
            for (int b = 0; b < BB; ++b) {
                float v = acc[q][b];
                #pragma unroll
                for (int o = 32; o >= 1; o >>= 1) v += __shfl_xor(v, o, 64);
                if (lane == 0)
                    mem2[(q * BB + b) * NBL + nb] = v + bfc[r] + bfv[r] + 0.05f;
            }
        }
    }

    // arrive: release mem2 stores, count this block
    __syncthreads();
    if (tid == 0) { __threadfence(); atomicAdd(&counters[0], 1u); }
    if (blk >= GEMB) return;                          // blocks 100..499 retire

    // barrier 1: wait all 500 GEMM blocks
    if (tid == 0) {
        while (__hip_atomic_load(&counters[0], __ATOMIC_ACQUIRE,
                                 __HIP_MEMORY_SCOPE_AGENT) < NBLK)
            __builtin_amdgcn_s_sleep(1);
    }
    __syncthreads();

    // ================= phase 2: exact order stats + spike (blocks 0..39, wave 0)
    if (blk < SELB && tid < 64) {
        const int b = blk / 5, k = blk - b * 5;
        const float* src = mem2 + (k * BB + b) * NBL;

        float    f[32];
        unsigned u[32];
        #pragma unroll
        for (int i = 0; i < 32; ++i) {
            int nb = i * 64 + lane;
            f[i] = (nb < NBL) ? src[nb] : 0.f;
            u[i] = (nb < NBL) ? sortkey(f[i]) : 0u;   // pad key = smallest
        }

        // rank-159 (160th largest): max X with count(u >= X) >= 160 (ballot+popc)
        unsigned X = 0;
        for (int bit = 31; bit >= 0; --bit) {
            unsigned cand = X | (1u << bit);
            int c = 0;
            #pragma unroll
            for (int i = 0; i < 32; ++i)
                c += (int)__popcll(__ballot(u[i] >= cand));
            if (c >= 160) X = cand;
        }
        const unsigned q2u = X;                       // mem_q2 (rank 159)

        int cge = 0;
        #pragma unroll
        for (int i = 0; i < 32; ++i)
            cge += (int)__popcll(__ballot(u[i] >= q2u));

        unsigned q1u;
        if (cge >= 161) {
            q1u = q2u;                                // ties reach rank 160
        } else {
            unsigned m = 0;
            #pragma unroll
            for (int i = 0; i < 32; ++i)
                if (u[i] < q2u && u[i] > m) m = u[i];
            #pragma unroll
            for (int o = 32; o >= 1; o >>= 1) {
                unsigned ot = __shfl_xor(m, o, 64);
                m = (ot > m) ? ot : m;
            }
            q1u = m;                                  // mem_q1 (rank 160)
        }

        const float q2 = unsortkey(q2u), q1 = unsortkey(q1u);
        const float nps = q1 + (q2 - q1) * 0.2f;

        #pragma unroll
        for (int i = 0; i < 32; ++i) {
            int nb = i * 64 + lane;
            if (nb < NBL)
                spike_out[b * RR + nb * 5 + k] = (f[i] - nps > 0.1f) ? 1.0f : 0.0f;
        }
        __threadfence();                              // release spike stores
        if (lane == 0) atomicAdd(&counters[1], 1u);
    }

    // barrier 2: wait all 40 select waves
    __syncthreads();
    if (tid == 0) {
        while (__hip_atomic_load(&counters[1], __ATOMIC_ACQUIRE,
                                 __HIP_MEMORY_SCOPE_AGENT) < SELB)
            __builtin_amdgcn_s_sleep(1);
    }
    __syncthreads();

    // ================= phase 3: GEMV  out[b][o] = spike[b]·W_mlp[o] + b_mlp[o]
    {
        const int o = blk;                            // blocks 0..99
        float acc[BB];
        #pragma unroll
        for (int b = 0; b < BB; ++b) acc[b] = 0.f;

        #pragma unroll
        for (int i = 0; i < 10; ++i) {
            int col = i * 1024 + tid * 4;             // 256 thr × f4 = 1024 floats/iter
            if (col < RR) {                           // last valid f4 at 9996
                float4 w = *(const float4*)(Wmlp + (size_t)o * RR + col);
                #pragma unroll
                for (int b = 0; b < BB; ++b) {
                    float4 s = *(const float4*)(spike_out + b * RR + col);
                    acc[b] += w.x * s.x + w.y * s.y + w.z * s.z + w.w * s.w;
                }
            }
        }

        __shared__ float red[4][BB];
        #pragma unroll
        for (int b = 0; b < BB; ++b) {
            float v = acc[b];
            #pragma unroll
            for (int off = 32; off >= 1; off >>= 1) v += __shfl_xor(v, off, 64);
            if (lane == 0) red[wave][b] = v;
        }
        __syncthreads();
        if (tid < BB) {
            float v = red[0][tid] + red[1][tid] + red[2][tid] + red[3][tid];
            out[tid * 100 + o] = v + bmlp[o];
        }
    }
}

extern "C" void kernel_launch(void* const* d_in, const int* in_sizes, int n_in,
                              void* d_out, int out_size, void* d_ws, size_t ws_size,
                              hipStream_t stream) {
    const float* in1  = (const float*)d_in[0];
    const float* in2  = (const float*)d_in[1];
    const float* in3  = (const float*)d_in[2];
    const float* in4  = (const float*)d_in[3];
    const float* in5  = (const float*)d_in[4];
    const float* Wfc  = (const float*)d_in[5];
    const float* bfc  = (const float*)d_in[6];
    // d_in[7] = W_fv : multiplied by zero spikes — never read (saves 400 MB)
    const float* bfv  = (const float*)d_in[8];
    const float* Wmlp = (const float*)d_in[9];
    const float* bmlp = (const float*)d_in[10];

    float* out   = (float*)d_out;          // 8*100 = 800 floats
    float* spike = out + 800;              // 8*10000 floats (r_sumspike)

    float*    mem2     = (float*)d_ws;     // 80000 floats, layout [q][b][nb]
    unsigned* counters = (unsigned*)((char*)d_ws + 80000 * sizeof(float));

    k_init<<<1, 64, 0, stream>>>(counters);
    k_fused<<<NBLK, 256, 0, stream>>>(in1, in2, in3, in4, in5, Wfc, bfc, bfv,
                                      Wmlp, bmlp, mem2, spike, out, counters);
}

// Round 6
// 83.373 us; speedup vs baseline: 2.3318x; 2.3318x over previous
//
#include <hip/hip_runtime.h>

#define BB   8
#define NBL  2000
#define RR   10000
#define XDIM 2000

// native vector type (clang builtin-compatible, unlike HIP_vector_type)
typedef float nfloat4 __attribute__((ext_vector_type(4)));

// ---------------- kernel A: mem2[k][b][nb] = x[b]·W_fc[r] + b_fc[r] + b_fv[r] + 0.05
// r = nb*5+k. 500 blocks × 256 thr, one nb per wave, NO LDS (x served from L1/L2).
// W_fc is read ONCE per call -> nontemporal loads (don't evict dirty poison lines).
__global__ __launch_bounds__(256) void kA_gemm(
    const float* __restrict__ in1, const float* __restrict__ in2,
    const float* __restrict__ in3, const float* __restrict__ in4,
    const float* __restrict__ in5,
    const float* __restrict__ Wfc, const float* __restrict__ bfc,
    const float* __restrict__ bfv, float* __restrict__ mem2,
    unsigned* __restrict__ counter)
{
    // re-arm the kernel-B barrier every call (kernel-boundary flush publishes it)
    if (blockIdx.x == 0 && threadIdx.x == 0) *counter = 0u;

    const int tid  = threadIdx.x;
    const int wave = tid >> 6, lane = tid & 63;
    const int nb    = blockIdx.x * 4 + wave;        // 0..1999
    const int rbase = nb * 5;

    float acc[5][BB];
    #pragma unroll
    for (int q = 0; q < 5; ++q)
        #pragma unroll
        for (int b = 0; b < BB; ++b) acc[q][b] = 0.f;

    #pragma unroll
    for (int i = 0; i < 8; ++i) {
        const int col = i * 256 + (lane << 2);      // 0..2044, float4-aligned
        const bool valid = col < XDIM;              // i==7 tail: lanes >=52 idle
        // per-lane x source: concat segment wh = col/400, offset within input
        const int wh  = col / 400;                  // 0..5 (5 only when invalid)
        const int off = col - wh * 400;             // float4 never crosses a 400-boundary
        const float* xp = in1;
        xp = (wh == 1) ? in2 : xp;
        xp = (wh == 2) ? in3 : xp;
        xp = (wh == 3) ? in4 : xp;
        xp = (wh == 4) ? in5 : xp;

        nfloat4 w[5];
        #pragma unroll
        for (int q = 0; q < 5; ++q)
            w[q] = valid ? __builtin_nontemporal_load(
                               (const nfloat4*)(Wfc + (size_t)(rbase + q) * XDIM + col))
                         : (nfloat4){0.f, 0.f, 0.f, 0.f};

        #pragma unroll
        for (int b = 0; b < BB; ++b) {
            nfloat4 xv = valid ? *(const nfloat4*)(xp + b * 400 + off)
                               : (nfloat4){0.f, 0.f, 0.f, 0.f};
            #pragma unroll
            for (int q = 0; q < 5; ++q)
                acc[q][b] += w[q].x * xv.x + w[q].y * xv.y + w[q].z * xv.z + w[q].w * xv.w;
        }
    }

    // cross-lane reduce (40 independent chains — ILP hides swizzle latency)
    #pragma unroll
    for (int q = 0; q < 5; ++q) {
        const int r = rbase + q;
        #pragma unroll
        for (int b = 0; b < BB; ++b) {
            float v = acc[q][b];
            #pragma unroll
            for (int o = 32; o >= 1; o >>= 1) v += __shfl_xor(v, o, 64);
            if (lane == 0)
                mem2[(q * BB + b) * NBL + nb] = v + bfc[r] + bfv[r] + 0.05f;
        }
    }
}

// ---------------- kernel B: fused {radix-select nps + spike} -> barrier -> MLP GEMV
__device__ __forceinline__ unsigned sortkey(float f) {
    unsigned u = __float_as_uint(f);
    return (u & 0x80000000u) ? ~u : (u | 0x80000000u);
}
__device__ __forceinline__ float unsortkey(unsigned u) {
    unsigned ub = (u & 0x80000000u) ? (u ^ 0x80000000u) : ~u;
    return __uint_as_float(ub);
}

__global__ __launch_bounds__(512) void kB_spike_out(
    const float* __restrict__ mem2, const float* __restrict__ Wmlp,
    const float* __restrict__ bmlp, float* __restrict__ spike_out,
    float* __restrict__ out, unsigned* __restrict__ counter)
{
    const int tid = threadIdx.x;
    const int blk = blockIdx.x;                      // 100 blocks

    // ---- phase A: blocks 0..39, wave 0 only — exact order stats + spike write
    if (blk < 40 && tid < 64) {
        const int b = blk / 5, k = blk - b * 5;
        const int lane = tid;
        const float* src = mem2 + (k * BB + b) * NBL;

        float    f[32];
        unsigned u[32];
        #pragma unroll
        for (int i = 0; i < 32; ++i) {
            int nb = i * 64 + lane;
            f[i] = (nb < NBL) ? src[nb] : 0.f;
            u[i] = (nb < NBL) ? sortkey(f[i]) : 0u;  // pad key = smallest
        }

        // rank-159 (160th largest): max X with count(u >= X) >= 160 (ballot+popc)
        unsigned X = 0;
        for (int bit = 31; bit >= 0; --bit) {
            unsigned cand = X | (1u << bit);
            int c = 0;
            #pragma unroll
            for (int i = 0; i < 32; ++i)
                c += (int)__popcll(__ballot(u[i] >= cand));
            if (c >= 160) X = cand;
        }
        const unsigned q2u = X;                      // mem_q2 (rank 159)

        int cge = 0;
        #pragma unroll
        for (int i = 0; i < 32; ++i)
            cge += (int)__popcll(__ballot(u[i] >= q2u));

        unsigned q1u;
        if (cge >= 161) {
            q1u = q2u;                               // ties reach rank 160
        } else {
            unsigned m = 0;
            #pragma unroll
            for (int i = 0; i < 32; ++i)
                if (u[i] < q2u && u[i] > m) m = u[i];
            #pragma unroll
            for (int o = 32; o >= 1; o >>= 1) {
                unsigned ot = __shfl_xor(m, o, 64);
                m = (ot > m) ? ot : m;
            }
            q1u = m;                                 // mem_q1 (rank 160)
        }

        const float q2 = unsortkey(q2u), q1 = unsortkey(q1u);
        const float nps = q1 + (q2 - q1) * 0.2f;

        #pragma unroll
        for (int i = 0; i < 32; ++i) {
            int nb = i * 64 + lane;
            if (nb < NBL)
                spike_out[b * RR + nb * 5 + k] = (f[i] - nps > 0.1f) ? 1.0f : 0.0f;
        }
        __threadfence();                             // release spike stores
        if (lane == 0) atomicAdd(counter, 1u);       // device-scope by default
    }

    // ---- barrier: all 100 blocks co-resident (<=256 CUs), spin on counter
    __syncthreads();
    if (tid == 0) {
        while (__hip_atomic_load(counter, __ATOMIC_ACQUIRE, __HIP_MEMORY_SCOPE_AGENT) < 40u)
            __builtin_amdgcn_s_sleep(2);
        __threadfence();                             // belt-and-braces acquire
    }
    __syncthreads();

    // ---- phase B: block = output column o; out[b][o] = spike[b]·W_mlp[o] + b_mlp[o]
    // W_mlp read once per call -> nontemporal.
    const int o = blk;
    const int wave = tid >> 6, lane = tid & 63;

    float acc[BB];
    #pragma unroll
    for (int b = 0; b < BB; ++b) acc[b] = 0.f;

    #pragma unroll
    for (int i = 0; i < 5; ++i) {
        int col = i * 2048 + tid * 4;                // 512 thr × f4 = 2048 floats/iter
        if (col < RR) {                              // last valid f4 at 9996
            nfloat4 w = __builtin_nontemporal_load(
                            (const nfloat4*)(Wmlp + (size_t)o * RR + col));
            #pragma unroll
            for (int b = 0; b < BB; ++b) {
                nfloat4 s = *(const nfloat4*)(spike_out + b * RR + col);
                acc[b] += w.x * s.x + w.y * s.y + w.z * s.z + w.w * s.w;
            }
        }
    }

    __shared__ float red[8][BB];
    #pragma unroll
    for (int b = 0; b < BB; ++b) {
        float v = acc[b];
        #pragma unroll
        for (int off = 32; off >= 1; off >>= 1) v += __shfl_xor(v, off, 64);
        if (lane == 0) red[wave][b] = v;
    }
    __syncthreads();
    if (tid < BB) {
        float v = 0.f;
        #pragma unroll
        for (int w = 0; w < 8; ++w) v += red[w][tid];
        out[tid * 100 + o] = v + bmlp[o];
    }
}

extern "C" void kernel_launch(void* const* d_in, const int* in_sizes, int n_in,
                              void* d_out, int out_size, void* d_ws, size_t ws_size,
                              hipStream_t stream) {
    const float* in1  = (const float*)d_in[0];
    const float* in2  = (const float*)d_in[1];
    const float* in3  = (const float*)d_in[2];
    const float* in4  = (const float*)d_in[3];
    const float* in5  = (const float*)d_in[4];
    const float* Wfc  = (const float*)d_in[5];
    const float* bfc  = (const float*)d_in[6];
    // d_in[7] = W_fv : multiplied by zero spikes — never read (saves 400 MB)
    const float* bfv  = (const float*)d_in[8];
    const float* Wmlp = (const float*)d_in[9];
    const float* bmlp = (const float*)d_in[10];

    float* out   = (float*)d_out;          // 8*100 = 800 floats
    float* spike = out + 800;              // 8*10000 floats (r_sumspike)

    float*    mem2    = (float*)d_ws;      // 80000 floats, layout [k][b][nb]
    unsigned* counter = (unsigned*)((char*)d_ws + 80000 * sizeof(float));

    kA_gemm<<<500, 256, 0, stream>>>(in1, in2, in3, in4, in5, Wfc, bfc, bfv,
                                     mem2, counter);
    kB_spike_out<<<100, 512, 0, stream>>>(mem2, Wmlp, bmlp, spike, out, counter);
}

// Round 7
// 67.068 us; speedup vs baseline: 2.8986x; 1.2431x over previous
//
#include <hip/hip_runtime.h>

#define BB   8
#define NBL  2000
#define RR   10000
#define XDIM 2000

// ---------------- kernel A (split-K): mem2[q][b][nb] = x[b]·W_fc[nb*5+q] + biases
// 1000 blocks × 256 thr. Block owns nb = blk*2 + {0,1}; each nb is computed by a
// PAIR of waves (column halves 0..1023 / 1024..1999) -> 4000 waves (~4/SIMD) for
// latency hiding; per-wave dependent chain halved (4 unrolled iters, not 8).
__global__ __launch_bounds__(256) void kA_gemm(
    const float* __restrict__ in1, const float* __restrict__ in2,
    const float* __restrict__ in3, const float* __restrict__ in4,
    const float* __restrict__ in5,
    const float* __restrict__ Wfc, const float* __restrict__ bfc,
    const float* __restrict__ bfv, float* __restrict__ mem2,
    unsigned* __restrict__ counter)
{
    // re-arm the kernel-B barrier every call (kernel-boundary flush publishes it)
    if (blockIdx.x == 0 && threadIdx.x == 0) *counter = 0u;

    const int tid  = threadIdx.x;
    const int wave = tid >> 6, lane = tid & 63;
    const int nbi  = wave >> 1;                     // 0..1: which nb in this block
    const int half = wave & 1;                      // 0..1: column half
    const int nb    = blockIdx.x * 2 + nbi;         // 0..1999
    const int rbase = nb * 5;

    float acc[5][BB];
    #pragma unroll
    for (int q = 0; q < 5; ++q)
        #pragma unroll
        for (int b = 0; b < BB; ++b) acc[q][b] = 0.f;

    #pragma unroll
    for (int i = 0; i < 4; ++i) {
        const int col = half * 1024 + i * 256 + (lane << 2);  // float4-aligned
        const bool valid = col < XDIM;              // tail: half==1,i==3, lanes>=52
        const int wh  = col / 400;                  // concat segment (5 only if invalid)
        const int off = col - wh * 400;             // f4 never crosses a 400-boundary
        const float* xp = in1;
        xp = (wh == 1) ? in2 : xp;
        xp = (wh == 2) ? in3 : xp;
        xp = (wh == 3) ? in4 : xp;
        xp = (wh == 4) ? in5 : xp;

        float4 w[5];
        #pragma unroll
        for (int q = 0; q < 5; ++q)
            w[q] = valid ? *(const float4*)(Wfc + (size_t)(rbase + q) * XDIM + col)
                         : make_float4(0.f, 0.f, 0.f, 0.f);

        #pragma unroll
        for (int b = 0; b < BB; ++b) {
            float4 xv = valid ? *(const float4*)(xp + b * 400 + off)
                              : make_float4(0.f, 0.f, 0.f, 0.f);
            #pragma unroll
            for (int q = 0; q < 5; ++q)
                acc[q][b] += w[q].x * xv.x + w[q].y * xv.y + w[q].z * xv.z + w[q].w * xv.w;
        }
    }

    // intra-wave reduce -> LDS partials -> half==0 wave finalizes
    __shared__ float part[2][2][5][BB];             // [nbi][half][q][b], 640 B
    #pragma unroll
    for (int q = 0; q < 5; ++q) {
        #pragma unroll
        for (int b = 0; b < BB; ++b) {
            float v = acc[q][b];
            #pragma unroll
            for (int o = 32; o >= 1; o >>= 1) v += __shfl_xor(v, o, 64);
            if (lane == 0) part[nbi][half][q][b] = v;
        }
    }
    __syncthreads();

    if (half == 0 && lane < 40) {                   // waves 0 and 2: 40 outputs each
        const int q = lane >> 3, b = lane & 7;
        const int r = rbase + q;
        const float v = part[nbi][0][q][b] + part[nbi][1][q][b];
        mem2[(q * BB + b) * NBL + nb] = v + bfc[r] + bfv[r] + 0.05f;
    }
}

// ---------------- kernel B: fused {radix-select nps + spike} -> barrier -> MLP GEMV
__device__ __forceinline__ unsigned sortkey(float f) {
    unsigned u = __float_as_uint(f);
    return (u & 0x80000000u) ? ~u : (u | 0x80000000u);
}
__device__ __forceinline__ float unsortkey(unsigned u) {
    unsigned ub = (u & 0x80000000u) ? (u ^ 0x80000000u) : ~u;
    return __uint_as_float(ub);
}

__global__ __launch_bounds__(512) void kB_spike_out(
    const float* __restrict__ mem2, const float* __restrict__ Wmlp,
    const float* __restrict__ bmlp, float* __restrict__ spike_out,
    float* __restrict__ out, unsigned* __restrict__ counter)
{
    const int tid = threadIdx.x;
    const int blk = blockIdx.x;                      // 100 blocks

    // ---- phase A: blocks 0..39, wave 0 only — exact order stats + spike write
    if (blk < 40 && tid < 64) {
        const int b = blk / 5, k = blk - b * 5;
        const int lane = tid;
        const float* src = mem2 + (k * BB + b) * NBL;

        float    f[32];
        unsigned u[32];
        #pragma unroll
        for (int i = 0; i < 32; ++i) {
            int nb = i * 64 + lane;
            f[i] = (nb < NBL) ? src[nb] : 0.f;
            u[i] = (nb < NBL) ? sortkey(f[i]) : 0u;  // pad key = smallest
        }

        // rank-159 (160th largest): max X with count(u >= X) >= 160 (ballot+popc)
        unsigned X = 0;
        for (int bit = 31; bit >= 0; --bit) {
            unsigned cand = X | (1u << bit);
            int c = 0;
            #pragma unroll
            for (int i = 0; i < 32; ++i)
                c += (int)__popcll(__ballot(u[i] >= cand));
            if (c >= 160) X = cand;
        }
        const unsigned q2u = X;                      // mem_q2 (rank 159)

        int cge = 0;
        #pragma unroll
        for (int i = 0; i < 32; ++i)
            cge += (int)__popcll(__ballot(u[i] >= q2u));

        unsigned q1u;
        if (cge >= 161) {
            q1u = q2u;                               // ties reach rank 160
        } else {
            unsigned m = 0;
            #pragma unroll
            for (int i = 0; i < 32; ++i)
                if (u[i] < q2u && u[i] > m) m = u[i];
            #pragma unroll
            for (int o = 32; o >= 1; o >>= 1) {
                unsigned ot = __shfl_xor(m, o, 64);
                m = (ot > m) ? ot : m;
            }
            q1u = m;                                 // mem_q1 (rank 160)
        }

        const float q2 = unsortkey(q2u), q1 = unsortkey(q1u);
        const float nps = q1 + (q2 - q1) * 0.2f;

        #pragma unroll
        for (int i = 0; i < 32; ++i) {
            int nb = i * 64 + lane;
            if (nb < NBL)
                spike_out[b * RR + nb * 5 + k] = (f[i] - nps > 0.1f) ? 1.0f : 0.0f;
        }
        __threadfence();                             // release spike stores
        if (lane == 0) atomicAdd(counter, 1u);       // device-scope by default
    }

    // ---- barrier: all 100 blocks co-resident (<=256 CUs), spin on counter
    __syncthreads();
    if (tid == 0) {
        while (__hip_atomic_load(counter, __ATOMIC_ACQUIRE, __HIP_MEMORY_SCOPE_AGENT) < 40u)
            __builtin_amdgcn_s_sleep(2);
        __threadfence();                             // belt-and-braces acquire
    }
    __syncthreads();

    // ---- phase B: block = output column o; out[b][o] = spike[b]·W_mlp[o] + b_mlp[o]
    const int o = blk;
    const int wave = tid >> 6, lane = tid & 63;

    float acc[BB];
    #pragma unroll
    for (int b = 0; b < BB; ++b) acc[b] = 0.f;

    #pragma unroll
    for (int i = 0; i < 5; ++i) {
        int col = i * 2048 + tid * 4;                // 512 thr × f4 = 2048 floats/iter
        if (col < RR) {                              // last valid f4 at 9996
            float4 w = *(const float4*)(Wmlp + (size_t)o * RR + col);
            #pragma unroll
            for (int b = 0; b < BB; ++b) {
                float4 s = *(const float4*)(spike_out + b * RR + col);
                acc[b] += w.x * s.x + w.y * s.y + w.z * s.z + w.w * s.w;
            }
        }
    }

    __shared__ float red[8][BB];
    #pragma unroll
    for (int b = 0; b < BB; ++b) {
        float v = acc[b];
        #pragma unroll
        for (int off = 32; off >= 1; off >>= 1) v += __shfl_xor(v, off, 64);
        if (lane == 0) red[wave][b] = v;
    }
    __syncthreads();
    if (tid < BB) {
        float v = 0.f;
        #pragma unroll
        for (int w = 0; w < 8; ++w) v += red[w][tid];
        out[tid * 100 + o] = v + bmlp[o];
    }
}

extern "C" void kernel_launch(void* const* d_in, const int* in_sizes, int n_in,
                              void* d_out, int out_size, void* d_ws, size_t ws_size,
                              hipStream_t stream) {
    const float* in1  = (const float*)d_in[0];
    const float* in2  = (const float*)d_in[1];
    const float* in3  = (const float*)d_in[2];
    const float* in4  = (const float*)d_in[3];
    const float* in5  = (const float*)d_in[4];
    const float* Wfc  = (const float*)d_in[5];
    const float* bfc  = (const float*)d_in[6];
    // d_in[7] = W_fv : multiplied by zero spikes — never read (saves 400 MB)
    const float* bfv  = (const float*)d_in[8];
    const float* Wmlp = (const float*)d_in[9];
    const float* bmlp = (const float*)d_in[10];

    float* out   = (float*)d_out;          // 8*100 = 800 floats
    float* spike = out + 800;              // 8*10000 floats (r_sumspike)

    float*    mem2    = (float*)d_ws;      // 80000 floats, layout [q][b][nb]
    unsigned* counter = (unsigned*)((char*)d_ws + 80000 * sizeof(float));

    kA_gemm<<<1000, 256, 0, stream>>>(in1, in2, in3, in4, in5, Wfc, bfc, bfv,
                                      mem2, counter);
    kB_spike_out<<<100, 512, 0, stream>>>(mem2, Wmlp, bmlp, spike, out, counter);
}

// Round 8
// 66.649 us; speedup vs baseline: 2.9169x; 1.0063x over previous
//
#include <hip/hip_runtime.h>

#define BB   8
#define NBL  2000
#define RR   10000
#define XDIM 2000

// ---------------- kernel A (split-K×4): mem2[q][b][nb] = x[b]·W_fc[nb*5+q] + biases
// 2000 blocks × 256 thr. Block owns ONE nb; its 4 waves cover 512-col quarters
// (2 unrolled iters each) -> 8000 waves (~8/SIMD = occupancy cap) for latency
// hiding; per-wave dependent chain = 2 iterations.
__global__ __launch_bounds__(256) void kA_gemm(
    const float* __restrict__ in1, const float* __restrict__ in2,
    const float* __restrict__ in3, const float* __restrict__ in4,
    const float* __restrict__ in5,
    const float* __restrict__ Wfc, const float* __restrict__ bfc,
    const float* __restrict__ bfv, float* __restrict__ mem2,
    unsigned* __restrict__ counter)
{
    // re-arm the kernel-B barrier every call (kernel-boundary flush publishes it)
    if (blockIdx.x == 0 && threadIdx.x == 0) *counter = 0u;

    const int tid  = threadIdx.x;
    const int wave = tid >> 6, lane = tid & 63;     // wave = column quarter 0..3
    const int nb    = blockIdx.x;                   // 0..1999
    const int rbase = nb * 5;

    float acc[5][BB];
    #pragma unroll
    for (int q = 0; q < 5; ++q)
        #pragma unroll
        for (int b = 0; b < BB; ++b) acc[q][b] = 0.f;

    #pragma unroll
    for (int i = 0; i < 2; ++i) {
        const int col = wave * 512 + i * 256 + (lane << 2);   // float4-aligned
        const bool valid = col < XDIM;              // tail: wave==3,i==1, lanes>=52
        const int wh  = col / 400;                  // concat segment (5 only if invalid)
        const int off = col - wh * 400;             // f4 never crosses a 400-boundary
        const float* xp = in1;
        xp = (wh == 1) ? in2 : xp;
        xp = (wh == 2) ? in3 : xp;
        xp = (wh == 3) ? in4 : xp;
        xp = (wh == 4) ? in5 : xp;

        float4 w[5];
        #pragma unroll
        for (int q = 0; q < 5; ++q)
            w[q] = valid ? *(const float4*)(Wfc + (size_t)(rbase + q) * XDIM + col)
                         : make_float4(0.f, 0.f, 0.f, 0.f);

        #pragma unroll
        for (int b = 0; b < BB; ++b) {
            float4 xv = valid ? *(const float4*)(xp + b * 400 + off)
                              : make_float4(0.f, 0.f, 0.f, 0.f);
            #pragma unroll
            for (int q = 0; q < 5; ++q)
                acc[q][b] += w[q].x * xv.x + w[q].y * xv.y + w[q].z * xv.z + w[q].w * xv.w;
        }
    }

    // intra-wave reduce -> LDS partials -> wave 0 finalizes
    __shared__ float part[4][5][BB];                // [wave][q][b], 640 B
    #pragma unroll
    for (int q = 0; q < 5; ++q) {
        #pragma unroll
        for (int b = 0; b < BB; ++b) {
            float v = acc[q][b];
            #pragma unroll
            for (int o = 32; o >= 1; o >>= 1) v += __shfl_xor(v, o, 64);
            if (lane == 0) part[wave][q][b] = v;
        }
    }
    __syncthreads();

    if (wave == 0 && lane < 40) {                   // 40 outputs: q = lane>>3, b = lane&7
        const int q = lane >> 3, b = lane & 7;
        const int r = rbase + q;
        const float v = part[0][q][b] + part[1][q][b] + part[2][q][b] + part[3][q][b];
        mem2[(q * BB + b) * NBL + nb] = v + bfc[r] + bfv[r] + 0.05f;
    }
}

// ---------------- kernel B: fused {radix-select nps + spike} -> barrier -> MLP GEMV
__device__ __forceinline__ unsigned sortkey(float f) {
    unsigned u = __float_as_uint(f);
    return (u & 0x80000000u) ? ~u : (u | 0x80000000u);
}
__device__ __forceinline__ float unsortkey(unsigned u) {
    unsigned ub = (u & 0x80000000u) ? (u ^ 0x80000000u) : ~u;
    return __uint_as_float(ub);
}

__global__ __launch_bounds__(512) void kB_spike_out(
    const float* __restrict__ mem2, const float* __restrict__ Wmlp,
    const float* __restrict__ bmlp, float* __restrict__ spike_out,
    float* __restrict__ out, unsigned* __restrict__ counter)
{
    const int tid = threadIdx.x;
    const int blk = blockIdx.x;                      // 100 blocks

    // ---- phase A: blocks 0..39, wave 0 only — exact order stats + spike write
    if (blk < 40 && tid < 64) {
        const int b = blk / 5, k = blk - b * 5;
        const int lane = tid;
        const float* src = mem2 + (k * BB + b) * NBL;

        float    f[32];
        unsigned u[32];
        #pragma unroll
        for (int i = 0; i < 32; ++i) {
            int nb = i * 64 + lane;
            f[i] = (nb < NBL) ? src[nb] : 0.f;
            u[i] = (nb < NBL) ? sortkey(f[i]) : 0u;  // pad key = smallest
        }

        // rank-159 (160th largest): max X with count(u >= X) >= 160 (ballot+popc)
        unsigned X = 0;
        for (int bit = 31; bit >= 0; --bit) {
            unsigned cand = X | (1u << bit);
            int c = 0;
            #pragma unroll
            for (int i = 0; i < 32; ++i)
                c += (int)__popcll(__ballot(u[i] >= cand));
            if (c >= 160) X = cand;
        }
        const unsigned q2u = X;                      // mem_q2 (rank 159)

        int cge = 0;
        #pragma unroll
        for (int i = 0; i < 32; ++i)
            cge += (int)__popcll(__ballot(u[i] >= q2u));

        unsigned q1u;
        if (cge >= 161) {
            q1u = q2u;                               // ties reach rank 160
        } else {
            unsigned m = 0;
            #pragma unroll
            for (int i = 0; i < 32; ++i)
                if (u[i] < q2u && u[i] > m) m = u[i];
            #pragma unroll
            for (int o = 32; o >= 1; o >>= 1) {
                unsigned ot = __shfl_xor(m, o, 64);
                m = (ot > m) ? ot : m;
            }
            q1u = m;                                 // mem_q1 (rank 160)
        }

        const float q2 = unsortkey(q2u), q1 = unsortkey(q1u);
        const float nps = q1 + (q2 - q1) * 0.2f;

        #pragma unroll
        for (int i = 0; i < 32; ++i) {
            int nb = i * 64 + lane;
            if (nb < NBL)
                spike_out[b * RR + nb * 5 + k] = (f[i] - nps > 0.1f) ? 1.0f : 0.0f;
        }
        __threadfence();                             // release spike stores
        if (lane == 0) atomicAdd(counter, 1u);       // device-scope by default
    }

    // ---- barrier: all 100 blocks co-resident (<=256 CUs), spin on counter
    __syncthreads();
    if (tid == 0) {
        while (__hip_atomic_load(counter, __ATOMIC_ACQUIRE, __HIP_MEMORY_SCOPE_AGENT) < 40u)
            __builtin_amdgcn_s_sleep(2);
        __threadfence();                             // belt-and-braces acquire
    }
    __syncthreads();

    // ---- phase B: block = output column o; out[b][o] = spike[b]·W_mlp[o] + b_mlp[o]
    const int o = blk;
    const int wave = tid >> 6, lane = tid & 63;

    float acc[BB];
    #pragma unroll
    for (int b = 0; b < BB; ++b) acc[b] = 0.f;

    #pragma unroll
    for (int i = 0; i < 5; ++i) {
        int col = i * 2048 + tid * 4;                // 512 thr × f4 = 2048 floats/iter
        if (col < RR) {                              // last valid f4 at 9996
            float4 w = *(const float4*)(Wmlp + (size_t)o * RR + col);
            #pragma unroll
            for (int b = 0; b < BB; ++b) {
                float4 s = *(const float4*)(spike_out + b * RR + col);
                acc[b] += w.x * s.x + w.y * s.y + w.z * s.z + w.w * s.w;
            }
        }
    }

    __shared__ float red[8][BB];
    #pragma unroll
    for (int b = 0; b < BB; ++b) {
        float v = acc[b];
        #pragma unroll
        for (int off = 32; off >= 1; off >>= 1) v += __shfl_xor(v, off, 64);
        if (lane == 0) red[wave][b] = v;
    }
    __syncthreads();
    if (tid < BB) {
        float v = 0.f;
        #pragma unroll
        for (int w = 0; w < 8; ++w) v += red[w][tid];
        out[tid * 100 + o] = v + bmlp[o];
    }
}

extern "C" void kernel_launch(void* const* d_in, const int* in_sizes, int n_in,
                              void* d_out, int out_size, void* d_ws, size_t ws_size,
                              hipStream_t stream) {
    const float* in1  = (const float*)d_in[0];
    const float* in2  = (const float*)d_in[1];
    const float* in3  = (const float*)d_in[2];
    const float* in4  = (const float*)d_in[3];
    const float* in5  = (const float*)d_in[4];
    const float* Wfc  = (const float*)d_in[5];
    const float* bfc  = (const float*)d_in[6];
    // d_in[7] = W_fv : multiplied by zero spikes — never read (saves 400 MB)
    const float* bfv  = (const float*)d_in[8];
    const float* Wmlp = (const float*)d_in[9];
    const float* bmlp = (const float*)d_in[10];

    float* out   = (float*)d_out;          // 8*100 = 800 floats
    float* spike = out + 800;              // 8*10000 floats (r_sumspike)

    float*    mem2    = (float*)d_ws;      // 80000 floats, layout [q][b][nb]
    unsigned* counter = (unsigned*)((char*)d_ws + 80000 * sizeof(float));

    kA_gemm<<<2000, 256, 0, stream>>>(in1, in2, in3, in4, in5, Wfc, bfc, bfv,
                                      mem2, counter);
    kB_spike_out<<<100, 512, 0, stream>>>(mem2, Wmlp, bmlp, spike, out, counter);
}